// Round 1
// baseline (116.417 us; speedup 1.0000x reference)
//
#include <hip/hip_runtime.h>
#include <hip/hip_fp16.h>
#include <cstdint>
#include <cstddef>

// z = soft_thresh(Toeplitz(v) @ x + W2 @ y, beta) -- complex, N=1024, M=256, B=1024
// Real embedding: C[1024][2048] = A'[1024][2560] @ B'[2560][2048] (layouts R0-R5).
// Output = Re(z) only: [1024,1024] f32 (R4 finding).
//
// R19: replace reg-staged LDS fill with global_load_lds (dwordx4, width=16).
// Key fix vs the failed R12 attempt: rule #21 (both-sides-or-neither swizzle).
// global_load_lds writes LINEARLY (wave base + lane*16), so the XOR swizzle
// moves to the per-lane GLOBAL SOURCE address; LDS dest is linear; the
// ds_read side keeps its existing XOR. LDS contents are bit-identical to R13.
// Removes 64 staging VGPRs + all ds_write_b128 traffic from the K-loop.
// build_all part-2 x/y loads vectorized to float4.

#define K_DIM 2560
#define BETA_F 0.01f
#define EPS_F  1e-12f

typedef __attribute__((ext_vector_type(8))) _Float16 half8;
typedef __attribute__((ext_vector_type(4))) _Float16 half4;
typedef __attribute__((ext_vector_type(4))) float   floatx4;

__device__ alignas(16) _Float16 g_Ap[1024 * K_DIM];      // 5 MB
__device__ alignas(16) _Float16 g_Bt[2048 * K_DIM];      // 10 MB

// ---------------- prep (merged): build A' and B' -----------------------------
__global__ __launch_bounds__(256) void build_all(
    const float* __restrict__ v_re, const float* __restrict__ v_im,
    const float* __restrict__ W2_re, const float* __restrict__ W2_im,
    const float* __restrict__ x_re, const float* __restrict__ x_im,
    const float* __restrict__ y_re, const float* __restrict__ y_im)
{
    const int bx = blockIdx.x;
    if (bx < 1280) {
        int t = bx * 256 + threadIdx.x;
        int i  = t / 320;
        int c  = t - i * 320;
        int kp = c * 8;                        // segment-aligned
        half8 h;
        if (kp < 1024) {
#pragma unroll
            for (int j = 0; j < 8; ++j) h[j] = (_Float16)v_re[1023 + i - kp - j];
        } else if (kp < 1280) {
            const float* s = W2_re + i * 256 + (kp - 1024);
#pragma unroll
            for (int j = 0; j < 8; ++j) h[j] = (_Float16)s[j];
        } else if (kp < 2304) {
            int k2 = kp - 1280;
#pragma unroll
            for (int j = 0; j < 8; ++j) h[j] = (_Float16)v_im[1023 + i - k2 - j];
        } else {
            const float* s = W2_im + i * 256 + (kp - 2304);
#pragma unroll
            for (int j = 0; j < 8; ++j) h[j] = (_Float16)s[j];
        }
        *reinterpret_cast<half8*>(g_Ap + (size_t)i * K_DIM + kp) = h;
        return;
    }
    __shared__ float lre[32][33];
    __shared__ float lim[32][33];
    int idx = bx - 1280;                       // 0..1279
    int bk  = idx % 40;
    int by  = idx / 40;
    const float* sre = (bk < 32) ? x_re : y_re;
    const float* sim = (bk < 32) ? x_im : y_im;
    int kb   = (bk < 32) ? bk : (bk - 32);
    int koff = (bk < 32) ? 0 : 1024;
    int k0 = kb * 32;
    int n0 = by * 32;
    int tid = threadIdx.x;
    {   // float4-vectorized transpose staging: 256 thr x 1 float4 per matrix
        int kk  = tid >> 3;                    // 0..31
        int tx4 = (tid & 7) * 4;               // 0,4,...,28
        const floatx4 re4 = *reinterpret_cast<const floatx4*>(
            sre + (size_t)(k0 + kk) * 1024 + n0 + tx4);
        const floatx4 im4 = *reinterpret_cast<const floatx4*>(
            sim + (size_t)(k0 + kk) * 1024 + n0 + tx4);
#pragma unroll
        for (int j = 0; j < 4; ++j) {
            lre[kk][tx4 + j] = re4[j];
            lim[kk][tx4 + j] = im4[j];
        }
    }
    __syncthreads();
    int lane_n = tid >> 3;
    int kq     = (tid & 7) * 4;
    half4 hre, him, hmim;
#pragma unroll
    for (int j = 0; j < 4; ++j) {
        float re = lre[kq + j][lane_n];
        float im = lim[kq + j][lane_n];
        hre[j]  = (_Float16)re;
        him[j]  = (_Float16)im;
        hmim[j] = (_Float16)(-im);
    }
    int n = n0 + lane_n;
    size_t kk2 = (size_t)koff + k0 + kq;
    _Float16* r0 = g_Bt + (size_t)(2 * n)     * K_DIM;
    _Float16* r1 = g_Bt + (size_t)(2 * n + 1) * K_DIM;
    *reinterpret_cast<half4*>(r0 + kk2)        = hre;
    *reinterpret_cast<half4*>(r0 + kk2 + 1280) = hmim;
    *reinterpret_cast<half4*>(r1 + kk2)        = him;
    *reinterpret_cast<half4*>(r1 + kk2 + 1280) = hre;
}

// ---------------- non-split GEMM + fused soft-threshold, BK=128 --------------
// 64x64 tile, BK=128 (4 ksub x 32k), 512 blocks (2/CU), 4 waves = 2x2 of 32x32.
// Dbuf LDS (32KB/buf, 1 barrier/iter), global_load_lds staging (linear dest,
// source-side XOR pre-swizzle), XOR swizzle on ds_read side unchanged.
__global__ __launch_bounds__(256, 2) void gemm_fused(float* __restrict__ out,
                                                     int out_n)
{
    __shared__ __align__(16) _Float16 As[2 * 4 * 64 * 32];  // [buf][ksub][row][32h]
    __shared__ __align__(16) _Float16 Bs[2 * 4 * 64 * 32];  // 16 KB each buf

    const int tid  = threadIdx.x;
    const int lane = tid & 63;
    const int w    = tid >> 6;
    const int wm   = w >> 1;
    const int wn   = w & 1;

    const int bid = blockIdx.x;          // 0..511
    const int xcd = bid & 7;             // round-robin -> XCD; 8x8 super-tile
    const int t   = bid >> 3;            // 0..63
    const int mi0 = ((xcd & 1) * 8 + (t & 7)) * 64;       // 0..960
    const int ni0 = ((xcd >> 1) * 8 + (t >> 3)) * 64;     // 0..1984

    floatx4 acc[2][2];
#pragma unroll
    for (int a = 0; a < 2; ++a)
#pragma unroll
        for (int b = 0; b < 2; ++b) acc[a][b] = (floatx4)0.0f;

    // staging decomposition: thread tid covers LDS bytes [tid*16, tid*16+16)
    // of each 4KB ksub slab (row = tid>>2, 16B chunk = tid&3). The XOR swizzle
    // that R13 applied to the LDS WRITE address is applied to the global
    // SOURCE chunk index instead -> identical LDS contents, linear DMA dest.
    const int rS = tid >> 2;                 // LDS row 0..63
    const int jS = tid & 3;                  // 16B chunk in 64B sub-row
    const int s0 = ((rS & 15) >> 1) & 3;
    const _Float16* gA = g_Ap + (size_t)(mi0 + rS) * K_DIM + (jS ^ s0) * 8;
    const _Float16* gB = g_Bt + (size_t)(ni0 + rS) * K_DIM + (jS ^ s0) * 8;
    char* asD = (char*)As + w * 1024;        // wave-uniform LDS base (+buf,+ks)
    char* bsD = (char*)Bs + w * 1024;

    const int rowA = lane & 15;
    const int q    = lane >> 4;
    const int coff = (q ^ ((rowA >> 1) & 3)) * 16;

    const int NIT = K_DIM / 128;         // 20

    auto stage = [&](int buf, int kt) {
        const _Float16* ga = gA + (size_t)kt * 128;
        const _Float16* gb = gB + (size_t)kt * 128;
        char* ad = asD + buf * 16384;
        char* bd = bsD + buf * 16384;
#pragma unroll
        for (int ks = 0; ks < 4; ++ks) {
            __builtin_amdgcn_global_load_lds(
                (const __attribute__((address_space(1))) void*)(ga + ks * 32),
                (__attribute__((address_space(3))) void*)(ad + ks * 4096),
                16, 0, 0);
            __builtin_amdgcn_global_load_lds(
                (const __attribute__((address_space(1))) void*)(gb + ks * 32),
                (__attribute__((address_space(3))) void*)(bd + ks * 4096),
                16, 0, 0);
        }
    };

    stage(0, 0);
    __syncthreads();

#pragma unroll 2
    for (int kt = 0; kt < NIT; ++kt) {
        const int cur = kt & 1;
        if (kt + 1 < NIT) stage(cur ^ 1, kt + 1);   // async DMA into nxt buf
        const char* Ab = (const char*)As + cur * 16384;
        const char* Bb = (const char*)Bs + cur * 16384;
#pragma unroll
        for (int ks = 0; ks < 4; ++ks) {
            half8 af[2], bf[2];
#pragma unroll
            for (int mi = 0; mi < 2; ++mi) {
                int r = wm * 32 + mi * 16 + rowA;
                af[mi] = *reinterpret_cast<const half8*>(Ab + ks * 4096 + r * 64 + coff);
            }
#pragma unroll
            for (int ni = 0; ni < 2; ++ni) {
                int r = wn * 32 + ni * 16 + rowA;
                bf[ni] = *reinterpret_cast<const half8*>(Bb + ks * 4096 + r * 64 + coff);
            }
#pragma unroll
            for (int mi = 0; mi < 2; ++mi)
#pragma unroll
                for (int ni = 0; ni < 2; ++ni)
                    acc[mi][ni] = __builtin_amdgcn_mfma_f32_16x16x32_f16(
                        af[mi], bf[ni], acc[mi][ni], 0, 0, 0);
        }
        __syncthreads();   // compiler drains vmcnt(0) here -> nxt buf ready
    }

    // epilogue: C/D col=lane&15, row=(lane>>4)*4+reg; lane^1 = re/im partner.
    // Output = Re(z) only: even C'-columns -> out[row*1024 + col/2].
    const int colL  = lane & 15;
    const int rquad = (lane >> 4) * 4;
#pragma unroll
    for (int mi = 0; mi < 2; ++mi)
#pragma unroll
        for (int ni = 0; ni < 2; ++ni)
#pragma unroll
            for (int r = 0; r < 4; ++r) {
                float c = acc[mi][ni][r];
                float p = __shfl_xor(c, 1, 64);
                float mag = sqrtf(c * c + p * p);
                float s = fmaxf(mag - BETA_F, 0.0f) / fmaxf(mag, EPS_F);
                int row = mi0 + wm * 32 + mi * 16 + rquad + r;
                int col = ni0 + wn * 32 + ni * 16 + colL;   // C' col (0..2047)
                if ((col & 1) == 0) {                        // even = Re lane
                    size_t idx = (size_t)row * 1024 + (col >> 1);
                    if (idx < (size_t)out_n) out[idx] = c * s;
                }
            }
}

// ---------------- launcher ---------------------------------------------------
extern "C" void kernel_launch(void* const* d_in, const int* in_sizes, int n_in,
                              void* d_out, int out_size, void* d_ws, size_t ws_size,
                              hipStream_t stream) {
    (void)d_ws; (void)ws_size; (void)in_sizes; (void)n_in;
    const float* v_re  = (const float*)d_in[0];
    const float* v_im  = (const float*)d_in[1];
    const float* W2_re = (const float*)d_in[2];
    const float* W2_im = (const float*)d_in[3];
    const float* x_re  = (const float*)d_in[4];
    const float* x_im  = (const float*)d_in[5];
    const float* y_re  = (const float*)d_in[6];
    const float* y_im  = (const float*)d_in[7];
    float* out = (float*)d_out;

    build_all<<<2560, 256, 0, stream>>>(v_re, v_im, W2_re, W2_im,
                                        x_re, x_im, y_re, y_im);
    gemm_fused<<<512, 256, 0, stream>>>(out, out_size);
}

// Round 3
// 108.357 us; speedup vs baseline: 1.0744x; 1.0744x over previous
//
#include <hip/hip_runtime.h>
#include <hip/hip_fp16.h>
#include <cstdint>
#include <cstddef>

// z = soft_thresh(Toeplitz(v) @ x + W2 @ y, beta) -- complex, N=1024, M=256, B=1024
// Real embedding: C[1024][2048] = A'[1024][2560] @ B'[2560][2048] (layouts R0-R5).
// Output = Re(z) only: [1024,1024] f32 (R4 finding).
//
// R21 = R20 resubmitted verbatim (R20 bench was a broker/container infra
// failure, no kernel signal; kernel re-audited: resources, swizzle algebra,
// K coverage, reduce layout all check out).
//
// R20: staging reverted to R13 reg-staged 2-deep (R19 post-mortem: DMA staging
// with 1-deep prefetch + vmcnt(0) barrier drain regressed +9us, reproducing R12;
// the reg pipeline's 2-iter depth is required at 2 blocks/CU).
// NEW: wave-level K-split inside the 64x64 tile. Each wave computes the FULL
// 64x64 output over its own K-quarter (ks = wave id) with 4x4 fragments:
// 8 ds_read_b128 / 16 MFMA per iter (ratio 0.5 vs R13's 1.0) -> K-loop LDS
// reads halve. One-time cross-wave reduce through LDS (reuses As/Bs space).

#define K_DIM 2560
#define BETA_F 0.01f
#define EPS_F  1e-12f

typedef __attribute__((ext_vector_type(8))) _Float16 half8;
typedef __attribute__((ext_vector_type(4))) _Float16 half4;
typedef __attribute__((ext_vector_type(4))) float   floatx4;

__device__ alignas(16) _Float16 g_Ap[1024 * K_DIM];      // 5 MB
__device__ alignas(16) _Float16 g_Bt[2048 * K_DIM];      // 10 MB

// ---------------- prep (merged): build A' and B' -----------------------------
__global__ __launch_bounds__(256) void build_all(
    const float* __restrict__ v_re, const float* __restrict__ v_im,
    const float* __restrict__ W2_re, const float* __restrict__ W2_im,
    const float* __restrict__ x_re, const float* __restrict__ x_im,
    const float* __restrict__ y_re, const float* __restrict__ y_im)
{
    const int bx = blockIdx.x;
    if (bx < 1280) {
        int t = bx * 256 + threadIdx.x;
        int i  = t / 320;
        int c  = t - i * 320;
        int kp = c * 8;                        // segment-aligned
        half8 h;
        if (kp < 1024) {
#pragma unroll
            for (int j = 0; j < 8; ++j) h[j] = (_Float16)v_re[1023 + i - kp - j];
        } else if (kp < 1280) {
            const float* s = W2_re + i * 256 + (kp - 1024);
#pragma unroll
            for (int j = 0; j < 8; ++j) h[j] = (_Float16)s[j];
        } else if (kp < 2304) {
            int k2 = kp - 1280;
#pragma unroll
            for (int j = 0; j < 8; ++j) h[j] = (_Float16)v_im[1023 + i - k2 - j];
        } else {
            const float* s = W2_im + i * 256 + (kp - 2304);
#pragma unroll
            for (int j = 0; j < 8; ++j) h[j] = (_Float16)s[j];
        }
        *reinterpret_cast<half8*>(g_Ap + (size_t)i * K_DIM + kp) = h;
        return;
    }
    __shared__ float lre[32][33];
    __shared__ float lim[32][33];
    int idx = bx - 1280;                       // 0..1279
    int bk  = idx % 40;
    int by  = idx / 40;
    const float* sre = (bk < 32) ? x_re : y_re;
    const float* sim = (bk < 32) ? x_im : y_im;
    int kb   = (bk < 32) ? bk : (bk - 32);
    int koff = (bk < 32) ? 0 : 1024;
    int k0 = kb * 32;
    int n0 = by * 32;
    int tid = threadIdx.x;
    {   // float4-vectorized transpose staging: 256 thr x 1 float4 per matrix
        int kk  = tid >> 3;                    // 0..31
        int tx4 = (tid & 7) * 4;               // 0,4,...,28
        const floatx4 re4 = *reinterpret_cast<const floatx4*>(
            sre + (size_t)(k0 + kk) * 1024 + n0 + tx4);
        const floatx4 im4 = *reinterpret_cast<const floatx4*>(
            sim + (size_t)(k0 + kk) * 1024 + n0 + tx4);
#pragma unroll
        for (int j = 0; j < 4; ++j) {
            lre[kk][tx4 + j] = re4[j];
            lim[kk][tx4 + j] = im4[j];
        }
    }
    __syncthreads();
    int lane_n = tid >> 3;
    int kq     = (tid & 7) * 4;
    half4 hre, him, hmim;
#pragma unroll
    for (int j = 0; j < 4; ++j) {
        float re = lre[kq + j][lane_n];
        float im = lim[kq + j][lane_n];
        hre[j]  = (_Float16)re;
        him[j]  = (_Float16)im;
        hmim[j] = (_Float16)(-im);
    }
    int n = n0 + lane_n;
    size_t kk2 = (size_t)koff + k0 + kq;
    _Float16* r0 = g_Bt + (size_t)(2 * n)     * K_DIM;
    _Float16* r1 = g_Bt + (size_t)(2 * n + 1) * K_DIM;
    *reinterpret_cast<half4*>(r0 + kk2)        = hre;
    *reinterpret_cast<half4*>(r0 + kk2 + 1280) = hmim;
    *reinterpret_cast<half4*>(r1 + kk2)        = him;
    *reinterpret_cast<half4*>(r1 + kk2 + 1280) = hre;
}

// ---------------- non-split GEMM + fused soft-threshold, BK=128 --------------
// 64x64 tile, BK=128 (4 ksub x 32k), 512 blocks (2/CU), 4 waves.
// Wave-K-split: wave w computes full 64x64 over ksub==w only (4x4 frags,
// 8 ds_read / 16 MFMA per iter). Dbuf LDS (1 barrier/iter), 2-deep register
// prefetch, XOR swizzle. Cross-wave partial-sum reduce via LDS at the end.
__global__ __launch_bounds__(256, 2) void gemm_fused(float* __restrict__ out,
                                                     int out_n)
{
    __shared__ __align__(16) char smem[65536];     // As[2][4][64][32h] | Bs[...]
    // after the K-loop, reused as float L[4][4][4][4][64] (w, mi, ni, r, lane)

    const int tid  = threadIdx.x;
    const int lane = tid & 63;
    const int w    = tid >> 6;

    const int bid = blockIdx.x;          // 0..511
    const int xcd = bid & 7;             // round-robin -> XCD; 8x8 super-tile
    const int t   = bid >> 3;            // 0..63
    const int mi0 = ((xcd & 1) * 8 + (t & 7)) * 64;       // 0..960
    const int ni0 = ((xcd >> 1) * 8 + (t >> 3)) * 64;     // 0..1984

    floatx4 acc[4][4];
#pragma unroll
    for (int a = 0; a < 4; ++a)
#pragma unroll
        for (int b = 0; b < 4; ++b) acc[a][b] = (floatx4)0.0f;

    const int rS = tid >> 2;                 // staging row 0..63
    const int jS = tid & 3;                  // 16B chunk in 64B sub-row
    const int s0 = ((rS & 15) >> 1) & 3;
    char* asW = smem         + rS * 64 + ((jS ^ s0) * 16);  // + buf*16384 + ks*4096
    char* bsW = smem + 32768 + rS * 64 + ((jS ^ s0) * 16);
    const _Float16* gA = g_Ap + (size_t)(mi0 + rS) * K_DIM + jS * 8;
    const _Float16* gB = g_Bt + (size_t)(ni0 + rS) * K_DIM + jS * 8;

    const int rowA = lane & 15;
    const int q    = lane >> 4;
    const int coff = (q ^ ((rowA >> 1) & 3)) * 16;

    const int NIT = K_DIM / 128;         // 20

    // 2-deep prefetch sets: set[(kt+1)&1] holds slab kt+1 during iter kt
    half8 sA[2][4], sB[2][4];

    {   // prologue: slab 0 -> LDS buf 0 (via temps); slab 1 -> set[1]
        half8 tA[4], tB[4];
#pragma unroll
        for (int ks = 0; ks < 4; ++ks) {
            tA[ks] = *reinterpret_cast<const half8*>(gA + ks * 32);
            tB[ks] = *reinterpret_cast<const half8*>(gB + ks * 32);
        }
#pragma unroll
        for (int ks = 0; ks < 4; ++ks) {
            sA[1][ks] = *reinterpret_cast<const half8*>(gA + 128 + ks * 32);
            sB[1][ks] = *reinterpret_cast<const half8*>(gB + 128 + ks * 32);
        }
#pragma unroll
        for (int ks = 0; ks < 4; ++ks) {
            *reinterpret_cast<half8*>(asW + ks * 4096) = tA[ks];
            *reinterpret_cast<half8*>(bsW + ks * 4096) = tB[ks];
        }
    }
    __syncthreads();

#pragma unroll 2
    for (int kt = 0; kt < NIT; ++kt) {
        const int cur = kt & 1;
        const int nxt = cur ^ 1;
        if (kt + 2 < NIT) {              // issue slab kt+2 into set[cur]
            const _Float16* ga = gA + (size_t)(kt + 2) * 128;
            const _Float16* gb = gB + (size_t)(kt + 2) * 128;
#pragma unroll
            for (int ks = 0; ks < 4; ++ks) {
                sA[cur][ks] = *reinterpret_cast<const half8*>(ga + ks * 32);
                sB[cur][ks] = *reinterpret_cast<const half8*>(gb + ks * 32);
            }
        }
        // compute: this wave's K-quarter (ksub = w), full 64x64 tile
        const char* Ab = smem         + cur * 16384 + w * 4096;
        const char* Bb = smem + 32768 + cur * 16384 + w * 4096;
        half8 af[4], bf[4];
#pragma unroll
        for (int mi = 0; mi < 4; ++mi)
            af[mi] = *reinterpret_cast<const half8*>(Ab + (mi * 16 + rowA) * 64 + coff);
#pragma unroll
        for (int ni = 0; ni < 4; ++ni)
            bf[ni] = *reinterpret_cast<const half8*>(Bb + (ni * 16 + rowA) * 64 + coff);
#pragma unroll
        for (int mi = 0; mi < 4; ++mi)
#pragma unroll
            for (int ni = 0; ni < 4; ++ni)
                acc[mi][ni] = __builtin_amdgcn_mfma_f32_16x16x32_f16(
                    af[mi], bf[ni], acc[mi][ni], 0, 0, 0);
        if (kt + 1 < NIT) {              // store slab kt+1 (loaded >=1 iter ago)
            char* aw = asW + nxt * 16384;
            char* bw = bsW + nxt * 16384;
#pragma unroll
            for (int ks = 0; ks < 4; ++ks) {
                *reinterpret_cast<half8*>(aw + ks * 4096) = sA[nxt][ks];
                *reinterpret_cast<half8*>(bw + ks * 4096) = sB[nxt][ks];
            }
        }
        __syncthreads();                 // single barrier per iter
    }

    // ---- cross-wave reduce (partial K-sums) via LDS, then fused threshold ---
    // L[w][mi][ni][r][lane] f32, 64KB exactly; lane-consecutive -> conflict-free.
    float* L = (float*)smem;
#pragma unroll
    for (int mi = 0; mi < 4; ++mi)
#pragma unroll
        for (int ni = 0; ni < 4; ++ni)
#pragma unroll
            for (int r = 0; r < 4; ++r)
                L[(((w * 4 + mi) * 4 + ni) * 4 + r) * 64 + lane] = acc[mi][ni][r];
    __syncthreads();

    // wave w reduces + thresholds row-block mi = w.
    // C/D frag map: col=lane&15, row=(lane>>4)*4+r; lane^1 = re/im partner.
    const int colL  = lane & 15;
    const int rquad = (lane >> 4) * 4;
#pragma unroll
    for (int ni = 0; ni < 4; ++ni)
#pragma unroll
        for (int r = 0; r < 4; ++r) {
            float c = 0.0f;
#pragma unroll
            for (int wp = 0; wp < 4; ++wp)
                c += L[(((wp * 4 + w) * 4 + ni) * 4 + r) * 64 + lane];
            float p = __shfl_xor(c, 1, 64);
            float mag = sqrtf(c * c + p * p);
            float s = fmaxf(mag - BETA_F, 0.0f) / fmaxf(mag, EPS_F);
            int row = mi0 + w * 16 + rquad + r;
            int col = ni0 + ni * 16 + colL;      // C' col (0..2047)
            if ((col & 1) == 0) {                // even = Re lane
                size_t idx = (size_t)row * 1024 + (col >> 1);
                if (idx < (size_t)out_n) out[idx] = c * s;
            }
        }
}

// ---------------- launcher ---------------------------------------------------
extern "C" void kernel_launch(void* const* d_in, const int* in_sizes, int n_in,
                              void* d_out, int out_size, void* d_ws, size_t ws_size,
                              hipStream_t stream) {
    (void)d_ws; (void)ws_size; (void)in_sizes; (void)n_in;
    const float* v_re  = (const float*)d_in[0];
    const float* v_im  = (const float*)d_in[1];
    const float* W2_re = (const float*)d_in[2];
    const float* W2_im = (const float*)d_in[3];
    const float* x_re  = (const float*)d_in[4];
    const float* x_im  = (const float*)d_in[5];
    const float* y_re  = (const float*)d_in[6];
    const float* y_im  = (const float*)d_in[7];
    float* out = (float*)d_out;

    build_all<<<2560, 256, 0, stream>>>(v_re, v_im, W2_re, W2_im,
                                        x_re, x_im, y_re, y_im);
    gemm_fused<<<512, 256, 0, stream>>>(out, out_size);
}

// Round 4
// 107.474 us; speedup vs baseline: 1.0832x; 1.0082x over previous
//
#include <hip/hip_runtime.h>
#include <hip/hip_fp16.h>
#include <cstdint>
#include <cstddef>

// z = soft_thresh(Toeplitz(v) @ x + W2 @ y, beta) -- complex, N=1024, M=256, B=1024
// Output = Re(z) only: [1024,1024] f32 (R4 finding).
//
// R22: Gauss 3-multiplication complex GEMM (pivot after R21 showed LDS reads
// not binding; R19 showed latency sensitivity -> keep reg-staged 2-deep).
//   m1 = Are@Bre, m2 = Aim@Bim, m3 = (Are+Aim)@(Bre+Bim), all K=1280 fp16.
//   Re = m1 - m2, Im = m3 - m1 - m2.  -25% FLOPs, fetch, LDS vs embedding.
// A-matrices [1024x1280] = [Toeplitz(v*), W2*]; B-matrices stored transposed
// [n=1024][k=1280] = [x*; y*]^T.  GEMM: 256 blocks (1/CU), 512 thr (8 waves,
// 2/SIMD), 64x64 tile, BK=64 dbuf (96KB LDS), waves = 2x2 spatial x 2 K-split,
// 2-way cross-wave reduce + fused soft-threshold epilogue (Re,Im same lane).

#define BETA_F 0.01f
#define EPS_F  1e-12f
#define ASZ (1024 * 1280)

typedef __attribute__((ext_vector_type(8))) _Float16 half8;
typedef __attribute__((ext_vector_type(4))) _Float16 half4;
typedef __attribute__((ext_vector_type(4))) float   floatx4;

__device__ alignas(16) _Float16 g_A[3 * ASZ];     // 7.86 MB: A1,A2,A3
__device__ alignas(16) _Float16 g_B[3 * ASZ];     // 7.86 MB: B1t,B2t,B3t

// ---------------- prep: build A1/A2/A3 and B1t/B2t/B3t -----------------------
__global__ __launch_bounds__(256) void build_all(
    const float* __restrict__ v_re, const float* __restrict__ v_im,
    const float* __restrict__ W2_re, const float* __restrict__ W2_im,
    const float* __restrict__ x_re, const float* __restrict__ x_im,
    const float* __restrict__ y_re, const float* __restrict__ y_im)
{
    const int bx = blockIdx.x;
    if (bx < 640) {                            // A-part: 1024x1280 / 8 per thread
        int t = bx * 256 + threadIdx.x;
        int i  = t / 160;
        int c  = t - i * 160;
        int kp = c * 8;                        // 0..1272, segment-aligned
        half8 h1, h2, h3;
        if (kp < 1024) {                       // Toeplitz zone
#pragma unroll
            for (int j = 0; j < 8; ++j) {
                float a = v_re[1023 + i - kp - j];
                float b = v_im[1023 + i - kp - j];
                h1[j] = (_Float16)a;
                h2[j] = (_Float16)b;
                h3[j] = (_Float16)(a + b);
            }
        } else {                               // W2 zone
            const float* sa = W2_re + i * 256 + (kp - 1024);
            const float* sb = W2_im + i * 256 + (kp - 1024);
#pragma unroll
            for (int j = 0; j < 8; ++j) {
                float a = sa[j], b = sb[j];
                h1[j] = (_Float16)a;
                h2[j] = (_Float16)b;
                h3[j] = (_Float16)(a + b);
            }
        }
        size_t base = (size_t)i * 1280 + kp;
        *reinterpret_cast<half8*>(g_A + base)           = h1;
        *reinterpret_cast<half8*>(g_A + ASZ + base)     = h2;
        *reinterpret_cast<half8*>(g_A + 2 * ASZ + base) = h3;
        return;
    }
    // B-part: transpose x/y 32x32 tiles -> B*t[n][k]
    __shared__ float lre[32][33];
    __shared__ float lim[32][33];
    int idx = bx - 640;                        // 0..1279
    int bk  = idx % 40;                        // k-tile (0..31 x, 32..39 y)
    int by  = idx / 40;                        // n-tile
    const float* sre = (bk < 32) ? x_re : y_re;
    const float* sim = (bk < 32) ? x_im : y_im;
    int krow0  = (bk < 32) ? bk * 32 : (bk - 32) * 32;     // row in source
    int kglob0 = (bk < 32) ? bk * 32 : 1024 + (bk - 32) * 32;
    int n0 = by * 32;
    int tid = threadIdx.x;
    {   // float4-vectorized staging
        int kk  = tid >> 3;                    // 0..31
        int tx4 = (tid & 7) * 4;
        const floatx4 re4 = *reinterpret_cast<const floatx4*>(
            sre + (size_t)(krow0 + kk) * 1024 + n0 + tx4);
        const floatx4 im4 = *reinterpret_cast<const floatx4*>(
            sim + (size_t)(krow0 + kk) * 1024 + n0 + tx4);
#pragma unroll
        for (int j = 0; j < 4; ++j) {
            lre[kk][tx4 + j] = re4[j];
            lim[kk][tx4 + j] = im4[j];
        }
    }
    __syncthreads();
    int lane_n = tid >> 3;                     // 0..31
    int kq     = (tid & 7) * 4;                // 0..28
    half4 h1, h2, h3;
#pragma unroll
    for (int j = 0; j < 4; ++j) {
        float re = lre[kq + j][lane_n];
        float im = lim[kq + j][lane_n];
        h1[j] = (_Float16)re;
        h2[j] = (_Float16)im;
        h3[j] = (_Float16)(re + im);
    }
    size_t base = (size_t)(n0 + lane_n) * 1280 + kglob0 + kq;
    *reinterpret_cast<half4*>(g_B + base)           = h1;
    *reinterpret_cast<half4*>(g_B + ASZ + base)     = h2;
    *reinterpret_cast<half4*>(g_B + 2 * ASZ + base) = h3;
}

// ---------------- Gauss GEMM + fused soft-threshold --------------------------
// 256 blocks (1/CU), 512 threads. 64x64 complex tile, K=1280, BK=64.
// LDS per buf: 6 slabs (A1..A3,B1..B3) x [2 kh][64 rows][32k=64B] = 48KB; dbuf.
// Wave w: wn=w&1, wm=(w>>1)&1 spatial quadrant (32x32); kh=w>>2 K-half.
// Per iter per wave: 3 products x (2+2 ds_read_b128 + 4 MFMA).
__global__ __launch_bounds__(512, 2) void gemm_fused(float* __restrict__ out,
                                                     int out_n)
{
    __shared__ __align__(16) char smem[98304];   // 2 x 49152

    const int tid  = threadIdx.x;
    const int lane = tid & 63;
    const int w    = tid >> 6;          // 0..7
    const int wn   = w & 1;
    const int wm   = (w >> 1) & 1;
    const int kh   = w >> 2;            // K-half 0/1

    const int bid = blockIdx.x;         // 0..255
    const int xcd = bid & 7;
    const int t   = bid >> 3;           // 0..31
    const int mi0 = ((xcd & 1) * 8 + (t & 7)) * 64;    // 16 row-tiles
    const int ni0 = ((xcd >> 1) * 4 + (t >> 3)) * 64;  // 16 col-tiles

    floatx4 acc[3][2][2];
#pragma unroll
    for (int p = 0; p < 3; ++p)
#pragma unroll
        for (int a = 0; a < 2; ++a)
#pragma unroll
            for (int b = 0; b < 2; ++b) acc[p][a][b] = (floatx4)0.0f;

    // staging: thread -> row rS (0..63), 16B chunk j8 of the 128B (BK=64) row
    const int rS  = tid >> 3;
    const int j8  = tid & 7;
    const int khS = j8 >> 2;            // which 32k half-slab
    const int jj  = j8 & 3;             // chunk within 64B half-row
    const int s0  = ((rS & 15) >> 1) & 3;
    const int wOff = khS * 4096 + rS * 64 + ((jj ^ s0) * 16);  // + buf*49152 + p*8192 (+24576 B)
    const _Float16* gA = g_A + (size_t)(mi0 + rS) * 1280 + khS * 32 + jj * 8;
    const _Float16* gB = g_B + (size_t)(ni0 + rS) * 1280 + khS * 32 + jj * 8;

    const int rowA = lane & 15;
    const int q    = lane >> 4;
    const int coff = (q ^ ((rowA >> 1) & 3)) * 16;

    const int NIT = 1280 / 64;          // 20

    half8 sA[2][3], sB[2][3];           // 2-deep prefetch sets

    {   // prologue: slab 0 -> LDS buf 0 via temps; slab 1 -> set[1]
        half8 tA[3], tB[3];
#pragma unroll
        for (int p = 0; p < 3; ++p) {
            tA[p] = *reinterpret_cast<const half8*>(gA + (size_t)p * ASZ);
            tB[p] = *reinterpret_cast<const half8*>(gB + (size_t)p * ASZ);
        }
#pragma unroll
        for (int p = 0; p < 3; ++p) {
            sA[1][p] = *reinterpret_cast<const half8*>(gA + (size_t)p * ASZ + 64);
            sB[1][p] = *reinterpret_cast<const half8*>(gB + (size_t)p * ASZ + 64);
        }
#pragma unroll
        for (int p = 0; p < 3; ++p) {
            *reinterpret_cast<half8*>(smem + p * 8192 + wOff)         = tA[p];
            *reinterpret_cast<half8*>(smem + 24576 + p * 8192 + wOff) = tB[p];
        }
    }
    __syncthreads();

#pragma unroll 2
    for (int kt = 0; kt < NIT; ++kt) {
        const int cur = kt & 1;
        const int nxt = cur ^ 1;
        if (kt + 2 < NIT) {             // issue slab kt+2 into set[cur]
#pragma unroll
            for (int p = 0; p < 3; ++p) {
                sA[cur][p] = *reinterpret_cast<const half8*>(
                    gA + (size_t)p * ASZ + (size_t)(kt + 2) * 64);
                sB[cur][p] = *reinterpret_cast<const half8*>(
                    gB + (size_t)p * ASZ + (size_t)(kt + 2) * 64);
            }
        }
        const char* base = smem + cur * 49152 + kh * 4096;
#pragma unroll
        for (int p = 0; p < 3; ++p) {
            half8 af[2], bf[2];
#pragma unroll
            for (int mi = 0; mi < 2; ++mi)
                af[mi] = *reinterpret_cast<const half8*>(
                    base + p * 8192 + (wm * 32 + mi * 16 + rowA) * 64 + coff);
#pragma unroll
            for (int ni = 0; ni < 2; ++ni)
                bf[ni] = *reinterpret_cast<const half8*>(
                    base + 24576 + p * 8192 + (wn * 32 + ni * 16 + rowA) * 64 + coff);
#pragma unroll
            for (int mi = 0; mi < 2; ++mi)
#pragma unroll
                for (int ni = 0; ni < 2; ++ni)
                    acc[p][mi][ni] = __builtin_amdgcn_mfma_f32_16x16x32_f16(
                        af[mi], bf[ni], acc[p][mi][ni], 0, 0, 0);
        }
        if (kt + 1 < NIT) {             // store slab kt+1 (loaded >=1 iter ago)
            char* wb = smem + nxt * 49152;
#pragma unroll
            for (int p = 0; p < 3; ++p) {
                *reinterpret_cast<half8*>(wb + p * 8192 + wOff)         = sA[nxt][p];
                *reinterpret_cast<half8*>(wb + 24576 + p * 8192 + wOff) = sB[nxt][p];
            }
        }
        __syncthreads();                // single barrier per iter
    }

    // ---- 2-way cross-wave K-reduce + Gauss combine + soft-threshold ---------
    // L[w4][p][mi][ni][r][lane] f32 = 48KB (reuses smem; K-loop done).
    float* L = (float*)smem;
    if (kh == 1) {
        const int w4 = w - 4;
#pragma unroll
        for (int p = 0; p < 3; ++p)
#pragma unroll
            for (int mi = 0; mi < 2; ++mi)
#pragma unroll
                for (int ni = 0; ni < 2; ++ni)
#pragma unroll
                    for (int r = 0; r < 4; ++r)
                        L[(((((w4 * 3 + p) * 2 + mi) * 2 + ni) * 4) + r) * 64 + lane]
                            = acc[p][mi][ni][r];
    }
    __syncthreads();
    if (kh == 0) {
        const int colL  = lane & 15;
        const int rquad = (lane >> 4) * 4;
#pragma unroll
        for (int mi = 0; mi < 2; ++mi)
#pragma unroll
            for (int ni = 0; ni < 2; ++ni)
#pragma unroll
                for (int r = 0; r < 4; ++r) {
                    float m0 = acc[0][mi][ni][r]
                        + L[((((w * 3 + 0) * 2 + mi) * 2 + ni) * 4 + r) * 64 + lane];
                    float m1 = acc[1][mi][ni][r]
                        + L[((((w * 3 + 1) * 2 + mi) * 2 + ni) * 4 + r) * 64 + lane];
                    float m2 = acc[2][mi][ni][r]
                        + L[((((w * 3 + 2) * 2 + mi) * 2 + ni) * 4 + r) * 64 + lane];
                    float re = m0 - m1;
                    float im = m2 - m0 - m1;
                    float mag = sqrtf(re * re + im * im);
                    float s = fmaxf(mag - BETA_F, 0.0f) / fmaxf(mag, EPS_F);
                    int row = mi0 + wm * 32 + mi * 16 + rquad + r;
                    int col = ni0 + wn * 32 + ni * 16 + colL;
                    size_t o = (size_t)row * 1024 + col;
                    if (o < (size_t)out_n) out[o] = re * s;
                }
    }
}

// ---------------- launcher ---------------------------------------------------
extern "C" void kernel_launch(void* const* d_in, const int* in_sizes, int n_in,
                              void* d_out, int out_size, void* d_ws, size_t ws_size,
                              hipStream_t stream) {
    (void)d_ws; (void)ws_size; (void)in_sizes; (void)n_in;
    const float* v_re  = (const float*)d_in[0];
    const float* v_im  = (const float*)d_in[1];
    const float* W2_re = (const float*)d_in[2];
    const float* W2_im = (const float*)d_in[3];
    const float* x_re  = (const float*)d_in[4];
    const float* x_im  = (const float*)d_in[5];
    const float* y_re  = (const float*)d_in[6];
    const float* y_im  = (const float*)d_in[7];
    float* out = (float*)d_out;

    build_all<<<1920, 256, 0, stream>>>(v_re, v_im, W2_re, W2_im,
                                        x_re, x_im, y_re, y_im);
    gemm_fused<<<256, 512, 0, stream>>>(out, out_size);
}